// Round 1
// baseline (1461.896 us; speedup 1.0000x reference)
//
#include <hip/hip_runtime.h>

// Power retention (deg-2), B=2 T=4096 H=16 D=64, CHUNK=64, E=2080.
// 3 kernels: intra (fp32), scan (bf16 MFMA, E split 8 ways), finalize.

#define B_ 2
#define T_ 4096
#define H_ 16
#define D_ 64
#define CHUNK_ 64
#define NCH_ 64          // T/CHUNK
#define E_ 2080
#define EH_ 8            // number of E-slices
#define ESL_ 260         // real E per slice
#define EPAD_ 288        // padded slice (9*32)
#define KT_ 96           // K-tile within slice
#define NKT_ 3           // 3*96 = 288
#define OUTN_ 8388608    // B*T*H*D

typedef __attribute__((ext_vector_type(8))) short short8;
typedef __attribute__((ext_vector_type(4))) float floatx4;

static __device__ __forceinline__ ushort f2b(float x) {
    union { float f; unsigned u; } un; un.f = x;
    unsigned r = un.u + 0x7FFFu + ((un.u >> 16) & 1u);   // RNE
    return (ushort)(r >> 16);
}
static __device__ __forceinline__ float b2f(ushort x) {
    union { unsigned u; float f; } un; un.u = ((unsigned)x) << 16; return un.f;
}

// ---------------- Kernel A: intra-chunk attention (fp32) ----------------
// grid 2048 = B*H*NCH. Writes num_intra -> out (base), den_intra -> den_buf.
__global__ __launch_bounds__(256) void intra_kernel(
    const float* __restrict__ q, const float* __restrict__ k, const float* __restrict__ v,
    const float* __restrict__ gate, float* __restrict__ out, float* __restrict__ den_buf)
{
    const int bid = blockIdx.x;
    const int n = bid & 63, h = (bid >> 6) & 15, b = bid >> 10;
    const int tid = threadIdx.x;
    const int lane = tid & 63, w = tid >> 6;
    const int t0 = n * CHUNK_;
    const int bh = b * H_ + h;

    __shared__ float qs[64 * 65];
    __shared__ float ks[64 * 65];
    __shared__ float ss[64 * 65];
    __shared__ float cgs[64];

    if (w == 0) {   // inclusive scan of gate over the chunk
        float g = gate[((size_t)(b * T_ + t0 + lane)) * H_ + h];
        #pragma unroll
        for (int off = 1; off < 64; off <<= 1) {
            float o = __shfl_up(g, off, 64);
            if (lane >= off) g += o;
        }
        cgs[lane] = g;
    }
    for (int idx = tid; idx < 4096; idx += 256) {
        int c = idx >> 6, d = idx & 63;
        size_t gi = ((size_t)(b * T_ + t0 + c) * H_ + h) * D_ + d;
        qs[c * 65 + d] = q[gi];
        ks[c * 65 + d] = k[gi];
    }
    __syncthreads();

    const int tc = tid & 15, tm = tid >> 4;   // 4 c's x 4 m's per thread
    float acc[4][4] = {};
    for (int d = 0; d < 64; ++d) {
        float qa[4], kb[4];
        #pragma unroll
        for (int i = 0; i < 4; ++i) qa[i] = qs[(tc * 4 + i) * 65 + d];
        #pragma unroll
        for (int i = 0; i < 4; ++i) kb[i] = ks[(tm * 4 + i) * 65 + d];
        #pragma unroll
        for (int i = 0; i < 4; ++i)
            #pragma unroll
            for (int j = 0; j < 4; ++j) acc[i][j] += qa[i] * kb[j];
    }
    #pragma unroll
    for (int i = 0; i < 4; ++i) {
        int c = tc * 4 + i;
        #pragma unroll
        for (int j = 0; j < 4; ++j) {
            int m = tm * 4 + j;
            float sv = 0.f;
            if (m <= c) {
                float qk = acc[i][j];
                sv = qk * qk * 0.015625f * __expf(cgs[c] - cgs[m]);  // (qk*0.125)^2 * dec
            }
            ss[c * 65 + m] = sv;
        }
    }
    __syncthreads();
    if (tid < 64) {
        float dsum = 0.f;
        for (int m = 0; m < 64; ++m) dsum += ss[tid * 65 + m];
        den_buf[(size_t)bh * T_ + t0 + tid] = dsum;
    }
    // reload v into qs (qk phase done with q)
    for (int idx = tid; idx < 4096; idx += 256) {
        int c = idx >> 6, d = idx & 63;
        qs[c * 65 + d] = v[((size_t)(b * T_ + t0 + c) * H_ + h) * D_ + d];
    }
    __syncthreads();
    float nacc[4][4] = {};
    for (int m = 0; m < 64; ++m) {
        float sa[4], vb[4];
        #pragma unroll
        for (int i = 0; i < 4; ++i) sa[i] = ss[(tc * 4 + i) * 65 + m];
        #pragma unroll
        for (int j = 0; j < 4; ++j) vb[j] = qs[m * 65 + tm * 4 + j];
        #pragma unroll
        for (int i = 0; i < 4; ++i)
            #pragma unroll
            for (int j = 0; j < 4; ++j) nacc[i][j] += sa[i] * vb[j];
    }
    #pragma unroll
    for (int i = 0; i < 4; ++i) {
        int c = tc * 4 + i;
        #pragma unroll
        for (int j = 0; j < 4; ++j) {
            int d = tm * 4 + j;
            out[((size_t)(b * T_ + t0 + c) * H_ + h) * D_ + d] = nacc[i][j];
        }
    }
}

// ---------------- Kernel B: sequential scan over chunks (bf16 MFMA) ----------------
// grid 256: block = (bh, eh). Owns S-slice [EPAD_ x 64] as bf16 transposed in LDS.
__global__ __launch_bounds__(256) void scan_kernel(
    const float* __restrict__ q, const float* __restrict__ k, const float* __restrict__ v,
    const float* __restrict__ gate, const float* __restrict__ S0, const float* __restrict__ sk0,
    float* __restrict__ den_buf, ushort* __restrict__ part)
{
    const int bid = blockIdx.x;
    const int eh = bid & 7, bh = bid >> 3;
    const int b = bh >> 4, h = bh & 15;
    const int tid = threadIdx.x, lane = tid & 63, w = tid >> 6;
    const int nlane = lane & 15, quad = lane >> 4;
    const int e0 = eh * ESL_;

    __shared__ __align__(16) ushort sT[64 * 296];      // S^T[d][e] bf16, row stride 296
    __shared__ __align__(16) ushort ptile[6912];       // pq: [c][kk] stride 104 | pkT: [kk][c] stride 72
    __shared__ ushort qs[64 * 65];                     // q then k chunk, bf16, row stride 65
    __shared__ ushort ijt[EPAD_];                      // (i<<8)|j, 0xFFFF = pad
    __shared__ float sk_s[EPAD_];
    __shared__ float cg_s[64], qdec_s[64], kdec_s[64];
    __shared__ float gse_s;

    // build (i,j) table for this slice (np.triu_indices order)
    for (int le = tid; le < EPAD_; le += 256) {
        ushort val = 0xFFFFu;
        if (le < ESL_) {
            int e = e0 + le;
            int i = (int)((129.0f - sqrtf(129.0f * 129.0f - 8.0f * (float)e)) * 0.5f);
            if (i < 0) i = 0;
            if (i > 63) i = 63;
            while (i > 0 && (i * (129 - i)) / 2 > e) --i;
            while (i < 63 && ((i + 1) * (128 - i)) / 2 <= e) ++i;
            int j = i + (e - (i * (129 - i)) / 2);
            val = (ushort)((i << 8) | j);
        }
        ijt[le] = val;
    }
    // load initial state (transposed, bf16) and sk (f32)
    for (int idx = tid; idx < EPAD_ * 64; idx += 256) {
        int le = idx >> 6, d = idx & 63;
        float sv = (le < ESL_) ? S0[((size_t)bh * E_ + e0 + le) * D_ + d] : 0.f;
        sT[d * 296 + le] = f2b(sv);
    }
    for (int le = tid; le < EPAD_; le += 256)
        sk_s[le] = (le < ESL_) ? sk0[(size_t)bh * E_ + e0 + le] : 0.f;
    __syncthreads();

    floatx4 accD[4];
    #pragma unroll
    for (int mt = 0; mt < 4; ++mt) {
        #pragma unroll
        for (int r = 0; r < 4; ++r) accD[mt][r] = 0.f;
    }
    float denacc[16];
    #pragma unroll
    for (int i = 0; i < 16; ++i) denacc[i] = 0.f;
    short8 vfr[4][2];

    for (int n = 0; n < NCH_; ++n) {
        const int t0 = n * CHUNK_;
        // gates (wave 0) + stage q (all)
        if (w == 0) {
            float g = gate[((size_t)(b * T_ + t0 + lane)) * H_ + h];
            #pragma unroll
            for (int off = 1; off < 64; off <<= 1) {
                float o = __shfl_up(g, off, 64);
                if (lane >= off) g += o;
            }
            cg_s[lane] = g;
            qdec_s[lane] = __expf(g);
            float gs = __shfl(g, 63, 64);
            kdec_s[lane] = __expf(gs - g);
            if (lane == 0) gse_s = __expf(gs);
        }
        for (int idx = tid; idx < 4096; idx += 256) {
            int c = idx >> 6, d = idx & 63;
            qs[c * 65 + d] = f2b(q[((size_t)(b * T_ + t0 + c) * H_ + h) * D_ + d]);
        }
        __syncthreads();

        // ---- phi(q) tiles + MM1: num_partial[c][d] += pq[c][e] * S[e][d]
        for (int kt = 0; kt < NKT_; ++kt) {
            #pragma unroll
            for (int blk = 0; blk < 2; ++blk) {
                int kk = blk * 64 + lane;           // e-local within K-tile
                if (kk < KT_) {
                    int le = kt * KT_ + kk;
                    ushort tv = ijt[le];
                    float skv = sk_s[le];
                    int ii = tv >> 8, jj = tv & 255;
                    float coef = 0.f;
                    if (tv != 0xFFFFu) coef = (ii == jj) ? 0.015625f : 0.02209708691f; // SCALE^2 (*sqrt2)
                    else { ii = 0; jj = 0; }
                    #pragma unroll
                    for (int cc4 = 0; cc4 < 16; ++cc4) {
                        int cc = cc4 * 4 + w;       // wave w owns c == w (mod 4)
                        float qi = b2f(qs[cc * 65 + ii]);
                        float qj = b2f(qs[cc * 65 + jj]);
                        float val = qi * qj * coef;
                        ptile[cc * 104 + kk] = f2b(val);
                        denacc[cc4] += val * skv;   // den partial rides phi-q
                    }
                }
            }
            __syncthreads();
            #pragma unroll
            for (int ks = 0; ks < 3; ++ks) {
                // B-frag: S[e][d], d = w*16+nlane (wave owns one d-tile)
                short8 bfr = *reinterpret_cast<const short8*>(
                    &sT[(w * 16 + nlane) * 296 + kt * KT_ + ks * 32 + quad * 8]);
                #pragma unroll
                for (int mt = 0; mt < 4; ++mt) {
                    short8 afr = *reinterpret_cast<const short8*>(
                        &ptile[(mt * 16 + nlane) * 104 + ks * 32 + quad * 8]);
                    accD[mt] = __builtin_amdgcn_mfma_f32_16x16x32_bf16(afr, bfr, accD[mt], 0, 0, 0);
                }
            }
            __syncthreads();
        }

        // den finalize: reduce over 64 lanes, scale by qdec, atomicAdd
        #pragma unroll
        for (int cc4 = 0; cc4 < 16; ++cc4) {
            float dsv = denacc[cc4];
            #pragma unroll
            for (int off = 1; off < 64; off <<= 1) dsv += __shfl_xor(dsv, off, 64);
            if (lane == 0) {
                int cc = cc4 * 4 + w;
                atomicAdd(&den_buf[(size_t)bh * T_ + t0 + cc], dsv * qdec_s[cc]);
            }
            denacc[cc4] = 0.f;
        }
        // num partial store (bf16), qdec applied
        #pragma unroll
        for (int mt = 0; mt < 4; ++mt) {
            #pragma unroll
            for (int r = 0; r < 4; ++r) {
                int c = mt * 16 + quad * 4 + r;     // C-frag row
                int d = w * 16 + nlane;             // C-frag col
                float pv = accD[mt][r] * qdec_s[c];
                part[(size_t)eh * OUTN_ + ((size_t)bh * T_ + t0 + c) * D_ + d] = f2b(pv);
                accD[mt][r] = 0.f;
            }
        }

        // ---- stage k into qs; v A-frags straight from global (L1/L2-hot)
        for (int idx = tid; idx < 4096; idx += 256) {
            int c = idx >> 6, d = idx & 63;
            qs[c * 65 + d] = f2b(k[((size_t)(b * T_ + t0 + c) * H_ + h) * D_ + d]);
        }
        #pragma unroll
        for (int mt = 0; mt < 4; ++mt) {
            #pragma unroll
            for (int ks = 0; ks < 2; ++ks) {
                short8 f;
                #pragma unroll
                for (int j2 = 0; j2 < 8; ++j2) {
                    int c = ks * 32 + quad * 8 + j2;   // K index
                    int d = mt * 16 + nlane;           // M index (v^T row)
                    f[j2] = (short)f2b(v[((size_t)(b * T_ + t0 + c) * H_ + h) * D_ + d]);
                }
                vfr[mt][ks] = f;
            }
        }
        __syncthreads();

        // ---- phi(k) tiles + MM2: S^T[d][e] = gse*S^T + v^T[d][c]*pk[c][e]; + sk update
        const float gse = gse_s;
        for (int kt = 0; kt < NKT_; ++kt) {
            float kd = kdec_s[lane];                   // lane = c here
            #pragma unroll
            for (int m = 0; m < 24; ++m) {
                int kk = w + m * 4;                    // e-local
                int le = kt * KT_ + kk;
                ushort tv = ijt[le];
                int ii = tv >> 8, jj = tv & 255;
                float coef = 0.f;
                if (tv != 0xFFFFu) coef = (ii == jj) ? 1.0f : 1.41421356237f;
                else { ii = 0; jj = 0; }
                float ki = b2f(qs[lane * 65 + ii]);
                float kj = b2f(qs[lane * 65 + jj]);
                ptile[kk * 72 + lane] = f2b(ki * kj * coef * kd);   // pkT[e][c]
            }
            __syncthreads();
            for (int nt = w; nt < 6; nt += 4) {        // e-subtiles of this K-tile
                #pragma unroll
                for (int mt = 0; mt < 4; ++mt) {
                    floatx4 cfr;
                    #pragma unroll
                    for (int r = 0; r < 4; ++r) {
                        int d = mt * 16 + quad * 4 + r;
                        int e = kt * KT_ + nt * 16 + nlane;
                        cfr[r] = b2f(sT[d * 296 + e]) * gse;       // decay folded into C-init
                    }
                    #pragma unroll
                    for (int ks = 0; ks < 2; ++ks) {
                        short8 bfr = *reinterpret_cast<const short8*>(
                            &ptile[(nt * 16 + nlane) * 72 + ks * 32 + quad * 8]);
                        cfr = __builtin_amdgcn_mfma_f32_16x16x32_bf16(vfr[mt][ks], bfr, cfr, 0, 0, 0);
                    }
                    #pragma unroll
                    for (int r = 0; r < 4; ++r) {
                        int d = mt * 16 + quad * 4 + r;
                        int e = kt * KT_ + nt * 16 + nlane;
                        sT[d * 296 + e] = f2b(cfr[r]);
                    }
                }
            }
            if (tid < KT_) {                            // sk slice update
                int le = kt * KT_ + tid;
                float rs = 0.f;
                #pragma unroll
                for (int cb = 0; cb < 8; ++cb) {
                    short8 pv = *reinterpret_cast<const short8*>(&ptile[tid * 72 + cb * 8]);
                    #pragma unroll
                    for (int j2 = 0; j2 < 8; ++j2) rs += b2f((ushort)pv[j2]);
                }
                sk_s[le] = sk_s[le] * gse + rs;
            }
            __syncthreads();
        }
    }
}

// ---------------- Kernel C: combine partials + divide ----------------
__global__ __launch_bounds__(256) void finalize_kernel(
    float* __restrict__ out, const float* __restrict__ den_buf, const ushort* __restrict__ part)
{
    size_t i = (size_t)blockIdx.x * 256 + threadIdx.x;   // OUTN_ total
    int d = (int)(i & 63);
    int h = (int)((i >> 6) & 15);
    int t = (int)((i >> 10) & 4095);
    int b = (int)(i >> 22);
    int bh = b * 16 + h;
    float sum = out[i];                                   // intra part
    size_t pbase = ((size_t)bh * T_ + t) * D_ + d;
    #pragma unroll
    for (int eh = 0; eh < 8; ++eh)
        sum += b2f(part[(size_t)eh * OUTN_ + pbase]);
    float den = den_buf[(size_t)bh * T_ + t];
    out[i] = sum / fmaxf(den, 1.0f);
}

extern "C" void kernel_launch(void* const* d_in, const int* in_sizes, int n_in,
                              void* d_out, int out_size, void* d_ws, size_t ws_size,
                              hipStream_t stream)
{
    (void)in_sizes; (void)n_in; (void)out_size; (void)ws_size;
    const float* q   = (const float*)d_in[0];
    const float* k   = (const float*)d_in[1];
    const float* v   = (const float*)d_in[2];
    const float* g   = (const float*)d_in[3];
    const float* S0  = (const float*)d_in[4];
    const float* sk0 = (const float*)d_in[5];
    float* out = (float*)d_out;

    // ws layout: den_buf [B*H*T] f32 (512KB) | part [8][B*H*T*D] bf16 (134.2MB)
    float* den_buf = (float*)d_ws;
    ushort* part = (ushort*)((char*)d_ws + (size_t)B_ * H_ * T_ * sizeof(float));

    intra_kernel<<<dim3(2048), dim3(256), 0, stream>>>(q, k, v, g, out, den_buf);
    scan_kernel<<<dim3(256), dim3(256), 0, stream>>>(q, k, v, g, S0, sk0, den_buf, part);
    finalize_kernel<<<dim3(OUTN_ / 256), dim3(256), 0, stream>>>(out, den_buf, part);
}

// Round 2
// 1018.153 us; speedup vs baseline: 1.4358x; 1.4358x over previous
//
#include <hip/hip_runtime.h>

// Power retention (deg-2), B=2 T=4096 H=16 D=64, CHUNK=64, E=2080.
// Round 2: scan restructured — blocked-e ordering (free permutation of the
// internal feature axis) so phi fragments build from 1 scalar + 1 b128 LDS
// read; owner-computes wave splits remove all intra-phase barriers
// (4 __syncthreads per chunk); 512-thread blocks give 2 waves/SIMD.

#define B_ 2
#define T_ 4096
#define H_ 16
#define D_ 64
#define CHUNK_ 64
#define NCH_ 64          // T/CHUNK
#define E_ 2080
#define EH_ 8            // E-slices (one block each per bh)
#define NBLK_ 36         // 8-wide j-blocks per slice (288 global / 8)
#define EPAD_ 288        // NBLK_*8 padded slice length
#define NTILE_ 18        // EPAD/16 MFMA e-tiles
#define STR_ 296         // sT row stride in ushorts (592B: 16B-aligned, 2-way banks)
#define QSTR_ 72         // qs row stride in ushorts (144B: 16B-aligned, 2-way banks)
#define OUTN_ 8388608    // B*T*H*D

typedef __attribute__((ext_vector_type(8))) short short8;
typedef __attribute__((ext_vector_type(4))) float floatx4;

static __device__ __forceinline__ ushort f2b(float x) {
    union { float f; unsigned u; } un; un.f = x;
    unsigned r = un.u + 0x7FFFu + ((un.u >> 16) & 1u);   // RNE
    return (ushort)(r >> 16);
}
static __device__ __forceinline__ float b2f(ushort x) {
    union { unsigned u; float f; } un; un.u = ((unsigned)x) << 16; return un.f;
}

// ---------------- Kernel A: intra-chunk attention (fp32) ----------------
__global__ __launch_bounds__(256) void intra_kernel(
    const float* __restrict__ q, const float* __restrict__ k, const float* __restrict__ v,
    const float* __restrict__ gate, float* __restrict__ out, float* __restrict__ den_buf)
{
    const int bid = blockIdx.x;
    const int n = bid & 63, h = (bid >> 6) & 15, b = bid >> 10;
    const int tid = threadIdx.x;
    const int lane = tid & 63, w = tid >> 6;
    const int t0 = n * CHUNK_;
    const int bh = b * H_ + h;

    __shared__ float qs[64 * 65];
    __shared__ float ks[64 * 65];
    __shared__ float ss[64 * 65];
    __shared__ float cgs[64];

    if (w == 0) {
        float g = gate[((size_t)(b * T_ + t0 + lane)) * H_ + h];
        #pragma unroll
        for (int off = 1; off < 64; off <<= 1) {
            float o = __shfl_up(g, off, 64);
            if (lane >= off) g += o;
        }
        cgs[lane] = g;
    }
    for (int idx = tid; idx < 4096; idx += 256) {
        int c = idx >> 6, d = idx & 63;
        size_t gi = ((size_t)(b * T_ + t0 + c) * H_ + h) * D_ + d;
        qs[c * 65 + d] = q[gi];
        ks[c * 65 + d] = k[gi];
    }
    __syncthreads();

    const int tc = tid & 15, tm = tid >> 4;
    float acc[4][4] = {};
    for (int d = 0; d < 64; ++d) {
        float qa[4], kb[4];
        #pragma unroll
        for (int i = 0; i < 4; ++i) qa[i] = qs[(tc * 4 + i) * 65 + d];
        #pragma unroll
        for (int i = 0; i < 4; ++i) kb[i] = ks[(tm * 4 + i) * 65 + d];
        #pragma unroll
        for (int i = 0; i < 4; ++i)
            #pragma unroll
            for (int j = 0; j < 4; ++j) acc[i][j] += qa[i] * kb[j];
    }
    #pragma unroll
    for (int i = 0; i < 4; ++i) {
        int c = tc * 4 + i;
        #pragma unroll
        for (int j = 0; j < 4; ++j) {
            int m = tm * 4 + j;
            float sv = 0.f;
            if (m <= c) {
                float qk = acc[i][j];
                sv = qk * qk * 0.015625f * __expf(cgs[c] - cgs[m]);
            }
            ss[c * 65 + m] = sv;
        }
    }
    __syncthreads();
    if (tid < 64) {
        float dsum = 0.f;
        for (int m = 0; m < 64; ++m) dsum += ss[tid * 65 + m];
        den_buf[(size_t)bh * T_ + t0 + tid] = dsum;
    }
    for (int idx = tid; idx < 4096; idx += 256) {
        int c = idx >> 6, d = idx & 63;
        qs[c * 65 + d] = v[((size_t)(b * T_ + t0 + c) * H_ + h) * D_ + d];
    }
    __syncthreads();
    float nacc[4][4] = {};
    for (int m = 0; m < 64; ++m) {
        float sa[4], vb[4];
        #pragma unroll
        for (int i = 0; i < 4; ++i) sa[i] = ss[(tc * 4 + i) * 65 + m];
        #pragma unroll
        for (int j = 0; j < 4; ++j) vb[j] = qs[m * 65 + tm * 4 + j];
        #pragma unroll
        for (int i = 0; i < 4; ++i)
            #pragma unroll
            for (int j = 0; j < 4; ++j) nacc[i][j] += sa[i] * vb[j];
    }
    #pragma unroll
    for (int i = 0; i < 4; ++i) {
        int c = tc * 4 + i;
        #pragma unroll
        for (int j = 0; j < 4; ++j) {
            int d = tm * 4 + j;
            out[((size_t)(b * T_ + t0 + c) * H_ + h) * D_ + d] = nacc[i][j];
        }
    }
}

// ---------------- Kernel B: sequential scan over chunks (bf16 MFMA) ----------------
// grid 256, block 512 (8 waves). block = (bh, eh). S-slice bf16 transposed in LDS.
// e within a slice is in blocked order: 36 blocks of (i, jb): e_local = t*8+jj
// corresponds to (i = blk_i[t], j = blk_jb[t]*8+jj), valid iff j >= i.
__global__ __launch_bounds__(512) void scan_kernel(
    const float* __restrict__ q, const float* __restrict__ k, const float* __restrict__ v,
    const float* __restrict__ gate, const float* __restrict__ S0, const float* __restrict__ sk0,
    float* __restrict__ den_buf, ushort* __restrict__ part)
{
    const int bid = blockIdx.x;
    const int eh = bid & 7, bh = bid >> 3;
    const int b = bh >> 4, h = bh & 15;
    const int tid = threadIdx.x, lane = tid & 63, w = tid >> 6;   // w: 0..7
    const int nlane = lane & 15, quad = lane >> 4;
    const int mt = w >> 1, ntp = w & 1;     // MM1 split: wave = (mt, nt-parity)

    __shared__ __align__(16) ushort sT[64 * STR_];   // S^T[d][e_local] bf16
    __shared__ __align__(16) ushort qs[64 * QSTR_];  // q- then k-chunk, bf16
    __shared__ float sk_s[EPAD_];
    __shared__ float cg_s[64], qdec_s[64], kdec_s[64];
    __shared__ float gse_sh;
    __shared__ int blk_i[NBLK_], blk_jb[NBLK_];

    if (tid == 0) {
        int g = 0;
        for (int i = 0; i < 64; ++i)
            for (int jb = (i >> 3); jb < 8; ++jb, ++g)
                if (g >= eh * NBLK_ && g < (eh + 1) * NBLK_) {
                    blk_i[g - eh * NBLK_] = i;
                    blk_jb[g - eh * NBLK_] = jb;
                }
    }
    __syncthreads();

    // load S0/sk0 with the blocked-e permutation; pads -> 0
    for (int idx = tid; idx < EPAD_ * 64; idx += 512) {
        int le = idx >> 6, d = idx & 63;
        int t = le >> 3, jj = le & 7;
        int i = blk_i[t], j = blk_jb[t] * 8 + jj;
        float sv = 0.f;
        if (j >= i) {
            int er = (i * (129 - i)) / 2 + (j - i);
            sv = S0[((size_t)bh * E_ + er) * D_ + d];
        }
        sT[d * STR_ + le] = f2b(sv);
    }
    for (int le = tid; le < EPAD_; le += 512) {
        int t = le >> 3, jj = le & 7;
        int i = blk_i[t], j = blk_jb[t] * 8 + jj;
        sk_s[le] = (j >= i) ? sk0[(size_t)bh * E_ + (i * (129 - i)) / 2 + (j - i)] : 0.f;
    }

    const float S2 = 0.015625f, S2R = 0.02209708691f;   // SCALE^2, SCALE^2*sqrt2

    for (int n = 0; n < NCH_; ++n) {
        const int t0 = n * CHUNK_;
        __syncthreads();   // prior MM2 done reading qs / writing sT, sk_s

        // ---- stage q chunk (bf16, packed u32 writes); wave 7 also does gates
        #pragma unroll
        for (int i = 0; i < 4; ++i) {
            int p = tid + i * 512;
            int c = p >> 5, d2 = (p & 31) * 2;
            const float* src = q + ((((size_t)(b * T_ + t0 + c)) * H_ + h) << 6) + d2;
            float x0 = src[0], x1 = src[1];
            unsigned pk2 = (unsigned)f2b(x0) | ((unsigned)f2b(x1) << 16);
            *reinterpret_cast<unsigned*>(&qs[c * QSTR_ + d2]) = pk2;
        }
        if (w == 7) {
            float g = gate[((size_t)(b * T_ + t0 + lane)) * H_ + h];
            #pragma unroll
            for (int off = 1; off < 64; off <<= 1) {
                float o = __shfl_up(g, off, 64);
                if (lane >= off) g += o;
            }
            cg_s[lane] = g;
            qdec_s[lane] = __expf(g);
            float gs = __shfl(g, 63, 64);
            kdec_s[lane] = __expf(gs - g);
            if (lane == 0) gse_sh = __expf(gs);
        }
        __syncthreads();

        // ---- MM1 (barrier-free): num[c][d] = pq[c][:] . S[:][d]; den rides along.
        // wave (mt, ntp): rows c = mt*16+.., cols d-tiles {ntp, ntp+2}.
        {
            floatx4 acc0 = {0.f, 0.f, 0.f, 0.f}, acc1 = {0.f, 0.f, 0.f, 0.f};
            float denacc = 0.f;
            const int c_row = mt * 16 + nlane;           // A-frag row (m = nlane)
            const int nt0 = ntp, nt1 = ntp + 2;
            #pragma unroll 3
            for (int ks = 0; ks < 9; ++ks) {
                int t = ks * 4 + quad;                   // e-block for this quad's k-range
                int ib = blk_i[t], jb8 = blk_jb[t] * 8;
                float qi = b2f(qs[c_row * QSTR_ + ib]);
                short8 qrow = *reinterpret_cast<const short8*>(&qs[c_row * QSTR_ + jb8]);
                short8 afr;
                #pragma unroll
                for (int j = 0; j < 8; ++j) {
                    int j8 = jb8 + j;
                    float cf = (j8 < ib) ? 0.f : ((j8 == ib) ? S2 : S2R);
                    float val = qi * b2f((ushort)qrow[j]) * cf;
                    afr[j] = (short)f2b(val);
                    if (ntp == 0) denacc += val * sk_s[t * 8 + j];
                }
                short8 b0 = *reinterpret_cast<const short8*>(
                    &sT[(nt0 * 16 + nlane) * STR_ + ks * 32 + quad * 8]);
                short8 b1 = *reinterpret_cast<const short8*>(
                    &sT[(nt1 * 16 + nlane) * STR_ + ks * 32 + quad * 8]);
                acc0 = __builtin_amdgcn_mfma_f32_16x16x32_bf16(afr, b0, acc0, 0, 0, 0);
                acc1 = __builtin_amdgcn_mfma_f32_16x16x32_bf16(afr, b1, acc1, 0, 0, 0);
            }
            if (ntp == 0) {   // den: reduce partials across quads, one atomic per row
                denacc += __shfl_xor(denacc, 16, 64);
                denacc += __shfl_xor(denacc, 32, 64);
                if (quad == 0)
                    atomicAdd(&den_buf[(size_t)bh * T_ + t0 + c_row], denacc * qdec_s[c_row]);
            }
            #pragma unroll
            for (int r = 0; r < 4; ++r) {
                int c = mt * 16 + quad * 4 + r;
                float qd = qdec_s[c];
                size_t base = (size_t)eh * OUTN_ + (((size_t)bh * T_ + t0 + c) << 6);
                part[base + nt0 * 16 + nlane] = f2b(acc0[r] * qd);
                part[base + nt1 * 16 + nlane] = f2b(acc1[r] * qd);
            }
        }
        __syncthreads();   // MM1 done reading qs before k overwrites it

        // ---- v A-fragments straight from global (L1/L2-hot), then stage k
        short8 vfr[4][2];
        #pragma unroll
        for (int mtv = 0; mtv < 4; ++mtv)
            #pragma unroll
            for (int ks = 0; ks < 2; ++ks) {
                short8 f;
                #pragma unroll
                for (int jj = 0; jj < 8; ++jj) {
                    int c = ks * 32 + quad * 8 + jj;
                    f[jj] = (short)f2b(v[((((size_t)(b * T_ + t0 + c)) * H_ + h) << 6)
                                         + mtv * 16 + nlane]);
                }
                vfr[mtv][ks] = f;
            }
        #pragma unroll
        for (int i = 0; i < 4; ++i) {
            int p = tid + i * 512;
            int c = p >> 5, d2 = (p & 31) * 2;
            const float* src = k + ((((size_t)(b * T_ + t0 + c)) * H_ + h) << 6) + d2;
            float x0 = src[0], x1 = src[1];
            unsigned pk2 = (unsigned)f2b(x0) | ((unsigned)f2b(x1) << 16);
            *reinterpret_cast<unsigned*>(&qs[c * QSTR_ + d2]) = pk2;
        }
        __syncthreads();

        // ---- MM2 (barrier-free): S^T[d][e] = gse*S^T + v^T[d][:] . pk[:][e]
        // wave owns e-tiles {w, w+8, w+16?} — sT columns & sk entries disjoint.
        const float gse = gse_sh;
        for (int nt = w; nt < NTILE_; nt += 8) {
            int tB = nt * 2 + (nlane >> 3);
            int ib = blk_i[tB];
            int j8 = blk_jb[tB] * 8 + (nlane & 7);
            float cf = (j8 < ib) ? 0.f : ((j8 == ib) ? 1.f : 1.41421356237f);
            float skacc = 0.f;
            short8 bfr[2];
            #pragma unroll
            for (int ks = 0; ks < 2; ++ks) {
                short8 f;
                #pragma unroll
                for (int jj = 0; jj < 8; ++jj) {
                    int c = ks * 32 + quad * 8 + jj;
                    float val = b2f(qs[c * QSTR_ + ib]) * b2f(qs[c * QSTR_ + j8])
                                * cf * kdec_s[c];
                    f[jj] = (short)f2b(val);
                    skacc += val;
                }
                bfr[ks] = f;
            }
            skacc += __shfl_xor(skacc, 16, 64);
            skacc += __shfl_xor(skacc, 32, 64);
            if (quad == 0) {
                int le = nt * 16 + nlane;
                sk_s[le] = sk_s[le] * gse + skacc;
            }
            #pragma unroll
            for (int mtv = 0; mtv < 4; ++mtv) {
                floatx4 cfr;
                #pragma unroll
                for (int r = 0; r < 4; ++r)
                    cfr[r] = b2f(sT[(mtv * 16 + quad * 4 + r) * STR_ + nt * 16 + nlane]) * gse;
                cfr = __builtin_amdgcn_mfma_f32_16x16x32_bf16(vfr[mtv][0], bfr[0], cfr, 0, 0, 0);
                cfr = __builtin_amdgcn_mfma_f32_16x16x32_bf16(vfr[mtv][1], bfr[1], cfr, 0, 0, 0);
                #pragma unroll
                for (int r = 0; r < 4; ++r)
                    sT[(mtv * 16 + quad * 4 + r) * STR_ + nt * 16 + nlane] = f2b(cfr[r]);
            }
        }
    }
}

// ---------------- Kernel C: combine partials + divide ----------------
__global__ __launch_bounds__(256) void finalize_kernel(
    float* __restrict__ out, const float* __restrict__ den_buf, const ushort* __restrict__ part)
{
    size_t i = (size_t)blockIdx.x * 256 + threadIdx.x;
    int d = (int)(i & 63);
    int h = (int)((i >> 6) & 15);
    int t = (int)((i >> 10) & 4095);
    int b = (int)(i >> 22);
    int bh = b * 16 + h;
    float sum = out[i];
    size_t pbase = ((size_t)bh * T_ + t) * D_ + d;
    #pragma unroll
    for (int eh = 0; eh < 8; ++eh)
        sum += b2f(part[(size_t)eh * OUTN_ + pbase]);
    float den = den_buf[(size_t)bh * T_ + t];
    out[i] = sum / fmaxf(den, 1.0f);
}

extern "C" void kernel_launch(void* const* d_in, const int* in_sizes, int n_in,
                              void* d_out, int out_size, void* d_ws, size_t ws_size,
                              hipStream_t stream)
{
    (void)in_sizes; (void)n_in; (void)out_size; (void)ws_size;
    const float* q   = (const float*)d_in[0];
    const float* k   = (const float*)d_in[1];
    const float* v   = (const float*)d_in[2];
    const float* g   = (const float*)d_in[3];
    const float* S0  = (const float*)d_in[4];
    const float* sk0 = (const float*)d_in[5];
    float* out = (float*)d_out;

    float* den_buf = (float*)d_ws;
    ushort* part = (ushort*)((char*)d_ws + (size_t)B_ * H_ * T_ * sizeof(float));

    intra_kernel<<<dim3(2048), dim3(256), 0, stream>>>(q, k, v, g, out, den_buf);
    scan_kernel<<<dim3(256), dim3(512), 0, stream>>>(q, k, v, g, S0, sk0, den_buf, part);
    finalize_kernel<<<dim3(OUTN_ / 256), dim3(256), 0, stream>>>(out, den_buf, part);
}

// Round 3
// 619.235 us; speedup vs baseline: 2.3608x; 1.6442x over previous
//
#include <hip/hip_runtime.h>

// Power retention (deg-2), B=2 T=4096 H=16 D=64, CHUNK=64, E=2080.
// Round 3: f16 pipeline. Scan grid = 32 bh x 8 eh x 2 d-half = 512 blocks
// (2/CU). All scalars folded into staged operands (q~ = 0.125*sqrt(qdec)*q,
// k~ = sqrt(kdec)*k, coef^2=2 as a {0,1,2} pk mask, sqrt2 into S0/sk0 load).
// S-slice resident in f32 VGPRs per owning wave; f16 copy in LDS for MM1.
// den + sk ride inside MFMAs (sk B-column / ones A-row). k~,v staged
// transposed for b128 B/A fragments. intra fused with finalize (runs last).

#define B_ 2
#define T_ 4096
#define H_ 16
#define D_ 64
#define CHUNK_ 64
#define NCH_ 64
#define E_ 2080
#define EH_ 8
#define NBLK_ 36         // (i, jb) 8-wide blocks per eh-slice (288/8, exact)
#define EPAD_ 288        // NBLK_*8
#define NKS_ 9           // MM1 K-steps of 32
#define NTILE_ 18        // 16-wide e-tiles
#define STR_ 296         // sT row stride (f16), 592B = 37*16
#define KTSTR_ 80        // k~^T row stride
#define QSTR_ 72         // q~ row stride
#define VSTR_ 72         // v^T row stride
#define OUTN_ 8388608    // B*T*H*D

typedef __attribute__((ext_vector_type(8))) _Float16 half8v;
typedef __attribute__((ext_vector_type(4))) float floatx4;

union U8 { half8v h; unsigned u[4]; ushort s[8]; };

static __device__ __forceinline__ float wave_iscan(float g, int lane) {
    #pragma unroll
    for (int off = 1; off < 64; off <<= 1) {
        float o = __shfl_up(g, off, 64);
        if (lane >= off) g += o;
    }
    return g;
}

// ---------------- Kernel B: sequential scan over chunks (f16 MFMA) ----------------
__global__ __launch_bounds__(512, 4) void scan_kernel(
    const float* __restrict__ q, const float* __restrict__ k, const float* __restrict__ v,
    const float* __restrict__ gate, const float* __restrict__ S0, const float* __restrict__ sk0,
    float* __restrict__ den_buf, _Float16* __restrict__ part)
{
    const int bid = blockIdx.x;
    // XCD swizzle: all 16 blocks of one bh share bid%8 -> same XCD for q/k/v L2 reuse
    const int bh = (bid & 7) * 4 + (bid >> 7);
    const int inner = (bid >> 3) & 15;
    const int eh = inner & 7, dh = inner >> 3;
    const int b = bh >> 4, h = bh & 15;
    const int tid = threadIdx.x, lane = tid & 63, w = tid >> 6;   // w 0..7
    const int nlane = lane & 15, quad = lane >> 4;

    __shared__ __align__(16) _Float16 sT[32 * STR_];     // S^T[d_local][e], f16 copy
    __shared__ __align__(16) _Float16 kT[64 * KTSTR_];   // k~^T[d][c]
    __shared__ __align__(16) _Float16 qsh[64 * QSTR_];   // q~[c][d]
    __shared__ __align__(16) _Float16 vTs[32 * VSTR_];   // v^T[d_local][c]
    __shared__ __align__(16) _Float16 sk_s[EPAD_];
    __shared__ __align__(16) _Float16 mask8_s[EPAD_];    // {0,1} valid-e mask
    __shared__ __align__(16) _Float16 mask2_s[EPAD_];    // {0,1,2} = coef^2 pk mask
    __shared__ int blk_s[NBLK_];                         // i | (jb<<8)

    // ---- build (i, jb) block table for this slice
    for (int t = tid; t < NBLK_; t += 512) {
        int g = eh * NBLK_ + t;
        int i = 0;
        while (g >= 8 - (i >> 3)) { g -= 8 - (i >> 3); ++i; }
        int jb = (i >> 3) + g;
        blk_s[t] = i | (jb << 8);
    }
    __syncthreads();

    // ---- masks + sk init (sqrt2 fold on off-diagonal)
    for (int e = tid; e < EPAD_; e += 512) {
        int bv = blk_s[e >> 3];
        int i = bv & 255, j8 = (bv >> 8) * 8 + (e & 7);
        mask2_s[e] = (_Float16)(j8 < i ? 0.f : (j8 == i ? 1.f : 2.f));
        mask8_s[e] = (_Float16)(j8 >= i ? 1.f : 0.f);
        float sv = 0.f;
        if (j8 >= i) {
            int er = (i * (129 - i)) / 2 + (j8 - i);
            float coef = (j8 == i) ? 1.f : 1.41421356237f;
            sv = sk0[(size_t)bh * E_ + er] * coef;
        }
        sk_s[e] = (_Float16)sv;
    }
    // ---- sT init (f16 copy of S-hat = coef * S0)
    for (int p = tid; p < 32 * EPAD_; p += 512) {
        int dl = p / EPAD_;
        int e = p - dl * EPAD_;
        int bv = blk_s[e >> 3];
        int i = bv & 255, j8 = (bv >> 8) * 8 + (e & 7);
        float sv = 0.f;
        if (j8 >= i) {
            int er = (i * (129 - i)) / 2 + (j8 - i);
            float coef = (j8 == i) ? 1.f : 1.41421356237f;
            sv = S0[((size_t)bh * E_ + er) * 64 + dh * 32 + dl] * coef;
        }
        sT[dl * STR_ + e] = (_Float16)sv;
    }

    // ---- resident S fragments (f32), fixed (tile, mtv) ownership
    const int NUN2 = (dh == 0) ? 54 : 36;   // 18 tiles x (2 d-tiles + sk-row on dh0)
    floatx4 res[7];
    #pragma unroll
    for (int uu = 0; uu < 7; ++uu) {
        res[uu] = (floatx4){0.f, 0.f, 0.f, 0.f};
        int u = w + 8 * uu;
        if (u >= NUN2) continue;
        int mtv = (u >= 36) ? 2 : ((u >= 18) ? 1 : 0);
        int tile = u - 18 * mtv;
        int e = tile * 16 + nlane;
        int bv = blk_s[e >> 3];
        int i = bv & 255, j8 = (bv >> 8) * 8 + (e & 7);
        if (j8 < i) continue;
        int er = (i * (129 - i)) / 2 + (j8 - i);
        float coef = (j8 == i) ? 1.f : 1.41421356237f;
        if (mtv < 2) {
            #pragma unroll
            for (int r = 0; r < 4; ++r)
                res[uu][r] = S0[((size_t)bh * E_ + er) * 64 + dh * 32 + mtv * 16 + quad * 4 + r] * coef;
        } else if (quad == 0) {
            res[uu][0] = sk0[(size_t)bh * E_ + er] * coef;
        }
    }

    // staging thread mapping: this thread stages column c=sc, d-group sd
    const int sc = w * 8 + (lane >> 3);
    const int sd = (lane & 7) * 8;

    // ---- gates chunk 0 (per wave, redundantly) + stage q~ chunk 0
    float cg_r, gs_r, gse_r;
    {
        float g = gate[((size_t)(b * T_) + lane) * H_ + h];
        cg_r = wave_iscan(g, lane);
        gs_r = __shfl(cg_r, 63, 64);
        gse_r = __expf(gs_r);
    }
    {
        float cgc = __shfl(cg_r, sc, 64);
        float qscale = 0.125f * __expf(0.5f * cgc);
        const float* src = q + ((size_t)(b * T_ + sc) * H_ + h) * 64 + sd;
        float4 a0 = *(const float4*)src;
        float4 a1 = *(const float4*)(src + 4);
        half8v hv;
        hv[0] = (_Float16)(a0.x * qscale); hv[1] = (_Float16)(a0.y * qscale);
        hv[2] = (_Float16)(a0.z * qscale); hv[3] = (_Float16)(a0.w * qscale);
        hv[4] = (_Float16)(a1.x * qscale); hv[5] = (_Float16)(a1.y * qscale);
        hv[6] = (_Float16)(a1.z * qscale); hv[7] = (_Float16)(a1.w * qscale);
        *(half8v*)&qsh[sc * QSTR_ + sd] = hv;
    }

    const int mt = w & 3;
    const int c_row = mt * 16 + nlane;
    const int NUN1 = (dh == 0) ? 12 : 8;
    const bool has_den = (w + 8) < NUN1;   // dh0, waves 0-3 carry the den unit
    const int nt0 = w >> 2;                // 0 or 1: this wave's d-tile

    for (int n = 0; n < NCH_; ++n) {
        const int t0 = n * CHUNK_;
        __syncthreads();   // B1: q~(n) staged + prev MM2 sT/sk writes visible

        // ======== MM1: num[c][d] = pq . S ; den rides as MFMA with sk column
        {
            floatx4 acc0 = {0.f, 0.f, 0.f, 0.f};
            floatx4 acc1 = {0.f, 0.f, 0.f, 0.f};
            #pragma unroll 3
            for (int ks = 0; ks < NKS_; ++ks) {
                int t = ks * 4 + quad;
                int bv = blk_s[t];
                int ib = bv & 255, jb8 = (bv >> 8) * 8;
                ushort qiu = ((const ushort*)qsh)[c_row * QSTR_ + ib];
                unsigned qi2 = ((unsigned)qiu << 16) | qiu;
                U8 qiv; qiv.u[0] = qi2; qiv.u[1] = qi2; qiv.u[2] = qi2; qiv.u[3] = qi2;
                half8v qrow = *(const half8v*)&qsh[c_row * QSTR_ + jb8];
                half8v m8 = *(const half8v*)&mask8_s[t * 8];
                half8v afr = qiv.h * qrow * m8;
                half8v b0 = *(const half8v*)&sT[(nt0 * 16 + nlane) * STR_ + ks * 32 + quad * 8];
                acc0 = __builtin_amdgcn_mfma_f32_16x16x32_f16(afr, b0, acc0, 0, 0, 0);
                if (has_den) {
                    half8v b1 = (half8v){0,0,0,0,0,0,0,0};
                    if (nlane == 0) b1 = *(const half8v*)&sk_s[ks * 32 + quad * 8];
                    acc1 = __builtin_amdgcn_mfma_f32_16x16x32_f16(afr, b1, acc1, 0, 0, 0);
                }
            }
            #pragma unroll
            for (int r = 0; r < 4; ++r) {
                int c = mt * 16 + quad * 4 + r;
                part[(size_t)eh * OUTN_ + (((size_t)bh * T_ + t0 + c) << 6) + dh * 32 + nt0 * 16 + nlane]
                    = (_Float16)acc0[r];
            }
            if (has_den && nlane == 0) {
                #pragma unroll
                for (int r = 0; r < 4; ++r)
                    atomicAdd(&den_buf[(size_t)bh * T_ + t0 + mt * 16 + quad * 4 + r], acc1[r]);
            }
        }

        // ======== stage k~^T (all d) and v^T (d-half), transposed
        {
            float cgc = __shfl(cg_r, sc, 64);
            float kscale = __expf(0.5f * (gs_r - cgc));
            const float* srck = k + ((size_t)(b * T_ + t0 + sc) * H_ + h) * 64 + sd;
            float4 k0 = *(const float4*)srck;
            float4 k1 = *(const float4*)(srck + 4);
            kT[(sd + 0) * KTSTR_ + sc] = (_Float16)(k0.x * kscale);
            kT[(sd + 1) * KTSTR_ + sc] = (_Float16)(k0.y * kscale);
            kT[(sd + 2) * KTSTR_ + sc] = (_Float16)(k0.z * kscale);
            kT[(sd + 3) * KTSTR_ + sc] = (_Float16)(k0.w * kscale);
            kT[(sd + 4) * KTSTR_ + sc] = (_Float16)(k1.x * kscale);
            kT[(sd + 5) * KTSTR_ + sc] = (_Float16)(k1.y * kscale);
            kT[(sd + 6) * KTSTR_ + sc] = (_Float16)(k1.z * kscale);
            kT[(sd + 7) * KTSTR_ + sc] = (_Float16)(k1.w * kscale);
            int vd = (lane & 7) * 4;   // local d row group (32 rows total)
            const float* srcv = v + ((size_t)(b * T_ + t0 + sc) * H_ + h) * 64 + dh * 32 + vd;
            float4 v0 = *(const float4*)srcv;
            vTs[(vd + 0) * VSTR_ + sc] = (_Float16)v0.x;
            vTs[(vd + 1) * VSTR_ + sc] = (_Float16)v0.y;
            vTs[(vd + 2) * VSTR_ + sc] = (_Float16)v0.z;
            vTs[(vd + 3) * VSTR_ + sc] = (_Float16)v0.w;
        }
        __syncthreads();   // B2: MM1 done with sT/qsh-reads; k~,v staged

        // ======== MM2: S-hat = gse*S-hat + v^T . pk ; sk rides as ones-row unit
        {
            const float gsev = gse_r;
            #pragma unroll
            for (int uu = 0; uu < 7; ++uu) {
                int u = w + 8 * uu;
                if (u >= NUN2) continue;
                int mtv = (u >= 36) ? 2 : ((u >= 18) ? 1 : 0);
                int tile = u - 18 * mtv;
                int e = tile * 16 + nlane;
                int bv = blk_s[e >> 3];
                int ib = bv & 255, j8 = (bv >> 8) * 8 + (e & 7);
                ushort m2u = ((const ushort*)mask2_s)[e];
                unsigned m22 = ((unsigned)m2u << 16) | m2u;
                U8 m2v; m2v.u[0] = m22; m2v.u[1] = m22; m2v.u[2] = m22; m2v.u[3] = m22;
                int rowi = ib * KTSTR_, rowj = j8 * KTSTR_;
                floatx4 c4;
                #pragma unroll
                for (int r = 0; r < 4; ++r) c4[r] = res[uu][r] * gsev;
                #pragma unroll
                for (int k2 = 0; k2 < 2; ++k2) {
                    int c0 = k2 * 32 + quad * 8;
                    half8v pa = *(const half8v*)&kT[rowi + c0];
                    half8v pb = *(const half8v*)&kT[rowj + c0];
                    half8v bfr = pa * pb * m2v.h;
                    half8v af;
                    if (mtv < 2) {
                        af = *(const half8v*)&vTs[(mtv * 16 + nlane) * VSTR_ + c0];
                    } else {
                        af = (nlane == 0) ? (half8v){1,1,1,1,1,1,1,1} : (half8v){0,0,0,0,0,0,0,0};
                    }
                    c4 = __builtin_amdgcn_mfma_f32_16x16x32_f16(af, bfr, c4, 0, 0, 0);
                }
                res[uu] = c4;
                if (mtv < 2) {
                    #pragma unroll
                    for (int r = 0; r < 4; ++r)
                        sT[(mtv * 16 + quad * 4 + r) * STR_ + e] = (_Float16)c4[r];
                } else if (quad == 0) {
                    sk_s[e] = (_Float16)c4[0];
                }
            }
        }

        // ======== gates(n+1) + stage q~(n+1) (qsh dead after MM1; safe vs MM2)
        if (n + 1 < NCH_) {
            float g = gate[((size_t)(b * T_ + (n + 1) * CHUNK_) + lane) * H_ + h];
            cg_r = wave_iscan(g, lane);
            gs_r = __shfl(cg_r, 63, 64);
            gse_r = __expf(gs_r);
            float cgc = __shfl(cg_r, sc, 64);
            float qscale = 0.125f * __expf(0.5f * cgc);
            const float* src = q + ((size_t)(b * T_ + (n + 1) * CHUNK_ + sc) * H_ + h) * 64 + sd;
            float4 a0 = *(const float4*)src;
            float4 a1 = *(const float4*)(src + 4);
            half8v hv;
            hv[0] = (_Float16)(a0.x * qscale); hv[1] = (_Float16)(a0.y * qscale);
            hv[2] = (_Float16)(a0.z * qscale); hv[3] = (_Float16)(a0.w * qscale);
            hv[4] = (_Float16)(a1.x * qscale); hv[5] = (_Float16)(a1.y * qscale);
            hv[6] = (_Float16)(a1.z * qscale); hv[7] = (_Float16)(a1.w * qscale);
            *(half8v*)&qsh[sc * QSTR_ + sd] = hv;
        }
    }
}

// ---------------- Kernel A+C: intra-chunk attention (fp32) + merge ----------------
__global__ __launch_bounds__(256) void intra_merge_kernel(
    const float* __restrict__ q, const float* __restrict__ k, const float* __restrict__ v,
    const float* __restrict__ gate, const float* __restrict__ den_buf,
    const _Float16* __restrict__ part, float* __restrict__ out)
{
    const int bid = blockIdx.x;
    const int n = bid & 63, h = (bid >> 6) & 15, b = bid >> 10;
    const int tid = threadIdx.x;
    const int lane = tid & 63, w = tid >> 6;
    const int t0 = n * CHUNK_;
    const int bh = b * H_ + h;

    __shared__ float qs2[64 * 68];
    __shared__ float ks2[64 * 68];
    __shared__ float ss[64 * 68];
    __shared__ float cgs[64];
    __shared__ float dens[64];

    if (w == 0) {
        float g = gate[((size_t)(b * T_ + t0) + lane) * H_ + h];
        cgs[lane] = wave_iscan(g, lane);
    }
    for (int idx = tid; idx < 1024; idx += 256) {
        int c = idx >> 4, d4 = (idx & 15) << 2;
        size_t gi = ((size_t)(b * T_ + t0 + c) * H_ + h) * 64 + d4;
        *(float4*)&qs2[c * 68 + d4] = *(const float4*)&q[gi];
        *(float4*)&ks2[c * 68 + d4] = *(const float4*)&k[gi];
    }
    __syncthreads();

    const int tc = tid & 15, tm = tid >> 4;
    float acc[4][4] = {};
    for (int d4 = 0; d4 < 64; d4 += 4) {
        float4 qa[4], kb[4];
        #pragma unroll
        for (int i = 0; i < 4; ++i) qa[i] = *(const float4*)&qs2[(tc * 4 + i) * 68 + d4];
        #pragma unroll
        for (int j = 0; j < 4; ++j) kb[j] = *(const float4*)&ks2[(tm * 4 + j) * 68 + d4];
        #pragma unroll
        for (int i = 0; i < 4; ++i)
            #pragma unroll
            for (int j = 0; j < 4; ++j)
                acc[i][j] += qa[i].x * kb[j].x + qa[i].y * kb[j].y
                           + qa[i].z * kb[j].z + qa[i].w * kb[j].w;
    }
    #pragma unroll
    for (int i = 0; i < 4; ++i) {
        int c = tc * 4 + i;
        #pragma unroll
        for (int j = 0; j < 4; ++j) {
            int m = tm * 4 + j;
            float sv = 0.f;
            if (m <= c) {
                float qk = acc[i][j];
                sv = qk * qk * 0.015625f * __expf(cgs[c] - cgs[m]);
            }
            ss[c * 68 + m] = sv;
        }
    }
    __syncthreads();
    if (tid < 64) {
        float dsum = 0.f;
        #pragma unroll 8
        for (int m = 0; m < 64; ++m) dsum += ss[tid * 68 + m];
        dens[tid] = dsum;
    }
    for (int idx = tid; idx < 1024; idx += 256) {
        int c = idx >> 4, d4 = (idx & 15) << 2;
        size_t gi = ((size_t)(b * T_ + t0 + c) * H_ + h) * 64 + d4;
        *(float4*)&qs2[c * 68 + d4] = *(const float4*)&v[gi];
    }
    __syncthreads();

    float nacc[4][4] = {};
    for (int m = 0; m < 64; ++m) {
        float4 vb = *(const float4*)&qs2[m * 68 + tm * 4];
        float sa[4];
        #pragma unroll
        for (int i = 0; i < 4; ++i) sa[i] = ss[(tc * 4 + i) * 68 + m];
        #pragma unroll
        for (int i = 0; i < 4; ++i) {
            nacc[i][0] += sa[i] * vb.x;
            nacc[i][1] += sa[i] * vb.y;
            nacc[i][2] += sa[i] * vb.z;
            nacc[i][3] += sa[i] * vb.w;
        }
    }
    #pragma unroll
    for (int i = 0; i < 4; ++i)
        #pragma unroll
        for (int j = 0; j < 4; ++j)
            ks2[(tc * 4 + i) * 68 + tm * 4 + j] = nacc[i][j];
    __syncthreads();

    for (int idx = tid; idx < 4096; idx += 256) {
        int c = idx >> 6, d = idx & 63;
        float sum = ks2[c * 68 + d];
        size_t pb = (((size_t)bh * T_ + t0 + c) << 6) + d;
        #pragma unroll
        for (int ehh = 0; ehh < EH_; ++ehh)
            sum += (float)part[(size_t)ehh * OUTN_ + pb];
        float den = dens[c] + den_buf[(size_t)bh * T_ + t0 + c];
        out[((size_t)(b * T_ + t0 + c) * H_ + h) * 64 + d] = sum / fmaxf(den, 1.0f);
    }
}

extern "C" void kernel_launch(void* const* d_in, const int* in_sizes, int n_in,
                              void* d_out, int out_size, void* d_ws, size_t ws_size,
                              hipStream_t stream)
{
    (void)in_sizes; (void)n_in; (void)out_size; (void)ws_size;
    const float* q   = (const float*)d_in[0];
    const float* k   = (const float*)d_in[1];
    const float* v   = (const float*)d_in[2];
    const float* g   = (const float*)d_in[3];
    const float* S0  = (const float*)d_in[4];
    const float* sk0 = (const float*)d_in[5];
    float* out = (float*)d_out;

    // ws: den_buf f32 [B*H*T] (512KB) | part f16 [EH][B*H*T*D] (134.2MB)
    float* den_buf = (float*)d_ws;
    _Float16* part = (_Float16*)((char*)d_ws + (size_t)B_ * H_ * T_ * sizeof(float));

    hipMemsetAsync(den_buf, 0, (size_t)B_ * H_ * T_ * sizeof(float), stream);
    scan_kernel<<<dim3(512), dim3(512), 0, stream>>>(q, k, v, g, S0, sk0, den_buf, part);
    intra_merge_kernel<<<dim3(2048), dim3(256), 0, stream>>>(q, k, v, g, den_buf, part, out);
}